// Round 3
// baseline (127.437 us; speedup 1.0000x reference)
//
#include <hip/hip_runtime.h>
#include <math.h>

#define NQ   10
#define DIM  1024
#define NB   10
#define NPTS 128
#define S2   0.70710678118654752440f

// ---------------------------------------------------------------------------
// helpers
// ---------------------------------------------------------------------------
__device__ __forceinline__ void cmul_ph(float& vr, float& vi, float ph) {
    float s, c;
    __sincosf(ph, &s, &c);
    const float ar = vr, ai = vi;
    vr = ar * c - ai * s;
    vi = ar * s + ai * c;
}

#define H_PAIR(i0, i1) {                                   \
    const float ar = vr[i0], ai = vi[i0];                  \
    const float br = vr[i1], bi = vi[i1];                  \
    vr[i0] = (ar + br) * S2;  vi[i0] = (ai + bi) * S2;     \
    vr[i1] = (ar - br) * S2;  vi[i1] = (ai - bi) * S2; }

#define RY_PAIR(i0, i1, c, s) {                            \
    const float ar = vr[i0], ai = vi[i0];                  \
    const float br = vr[i1], bi = vi[i1];                  \
    vr[i0] = c * ar - s * br;  vi[i0] = c * ai - s * bi;   \
    vr[i1] = s * ar + c * br;  vi[i1] = s * ai + c * bi; }

// ---------------------------------------------------------------------------
// Kernel A: simulate psi(x) = F(x, params)|0>. One block (256 thr) per point.
// State fully in registers: 4 amps/thread.
//   canonical layout : d = w*256 + lane*4 + r   (reg bits = d-bits [1:0])
//   transposed layout: d = k*256 + lane*4 + w   (reg bits = d-bits [9:8])
// Qubit q acts on d-bit p = 9-q. Double-buffered transpose LDS: 2 barriers
// per circuit block (write;sync;read on alternating buffers).
// ---------------------------------------------------------------------------
__global__ __launch_bounds__(256)
void states_kernel(const float* __restrict__ data,
                   const float* __restrict__ params,
                   float2* __restrict__ psi,
                   double* __restrict__ acc,
                   int* __restrict__ cnt)
{
    __shared__ float aRe[DIM];
    __shared__ float aIm[DIM];
    __shared__ float bRe[DIM];
    __shared__ float bIm[DIM];

    const int tid  = threadIdx.x;
    const int w    = tid >> 6;
    const int lane = tid & 63;
    const int pt   = blockIdx.x;

    const int cbase = w * 256 + lane * 4;  // canonical amps: cbase + r
    const int tb    = lane * 4 + w;        // transposed amps: k*256 + tb

    if (pt == 0 && tid == 0) { acc[0] = 0.0; acc[1] = 0.0; cnt[0] = 0; }

    float vr[4], vi[4];
    vr[0] = vr[1] = vr[2] = vr[3] = 0.f;
    vi[0] = vi[1] = vi[2] = vi[3] = 0.f;
    if (tid == 0) vr[0] = 1.f;

    const float* x = data + pt * (NB * NQ);

    for (int j = 0; j < NB; ++j) {
        const float* ry  = params + j * 2 * NQ;  // RY angles
        const float* crz = ry + NQ;              // CRZ angles
        const float* xb  = x + j * NQ;           // RZ angles (data)

        // ================= H layer =================
        // canonical local: d-bits 1,0  (q = 8, 9)
        H_PAIR(0, 2) H_PAIR(1, 3)
        H_PAIR(0, 1) H_PAIR(2, 3)
        // lane bits: d-bit 2+l  (q = 7-l)
        #pragma unroll
        for (int l = 0; l < 6; ++l) {
            const float sg = ((lane >> l) & 1) ? -1.f : 1.f;
            #pragma unroll
            for (int r = 0; r < 4; ++r) {
                const float ur = __shfl_xor(vr[r], 1 << l, 64);
                const float ui = __shfl_xor(vi[r], 1 << l, 64);
                vr[r] = (ur + sg * vr[r]) * S2;
                vi[r] = (ui + sg * vi[r]) * S2;
            }
        }
        // transpose canonical -> transposed (buffer A)
        *(float4*)&aRe[cbase] = make_float4(vr[0], vr[1], vr[2], vr[3]);
        *(float4*)&aIm[cbase] = make_float4(vi[0], vi[1], vi[2], vi[3]);
        __syncthreads();
        #pragma unroll
        for (int k = 0; k < 4; ++k) { vr[k] = aRe[k * 256 + tb]; vi[k] = aIm[k * 256 + tb]; }
        // transposed local: d-bits 9,8  (q = 0, 1)
        H_PAIR(0, 2) H_PAIR(1, 3)
        H_PAIR(0, 1) H_PAIR(2, 3)

        // ================= RZ diagonal (transposed) =================
        {
            const float x0 = xb[0], x1 = xb[1];
            float base_ph = -0.5f * (x0 + x1);
            #pragma unroll
            for (int q = 2; q < NQ; ++q)
                base_ph += (((tb >> (9 - q)) & 1) - 0.5f) * xb[q];
            cmul_ph(vr[0], vi[0], base_ph);
            cmul_ph(vr[1], vi[1], base_ph + x1);        // reg bit0 = d-bit8 = q1
            cmul_ph(vr[2], vi[2], base_ph + x0);        // reg bit1 = d-bit9 = q0
            cmul_ph(vr[3], vi[3], base_ph + x0 + x1);
        }

        // ================= RY layer =================
        // transposed local: q=0 (reg bit1), q=1 (reg bit0)
        {
            float c, s;
            __sincosf(ry[0] * 0.5f, &s, &c);
            RY_PAIR(0, 2, c, s) RY_PAIR(1, 3, c, s)
            __sincosf(ry[1] * 0.5f, &s, &c);
            RY_PAIR(0, 1, c, s) RY_PAIR(2, 3, c, s)
        }
        // lane bits: d-bit 2+l  (q = 7-l)
        #pragma unroll
        for (int l = 0; l < 6; ++l) {
            float c, s;
            __sincosf(ry[7 - l] * 0.5f, &s, &c);
            const float ss = ((lane >> l) & 1) ? s : -s;
            #pragma unroll
            for (int r = 0; r < 4; ++r) {
                const float ur = __shfl_xor(vr[r], 1 << l, 64);
                const float ui = __shfl_xor(vi[r], 1 << l, 64);
                vr[r] = c * vr[r] + ss * ur;
                vi[r] = c * vi[r] + ss * ui;
            }
        }
        // transpose back transposed -> canonical (buffer B)
        #pragma unroll
        for (int k = 0; k < 4; ++k) { bRe[k * 256 + tb] = vr[k]; bIm[k * 256 + tb] = vi[k]; }
        __syncthreads();
        {
            const float4 fr = *(const float4*)&bRe[cbase];
            const float4 fi = *(const float4*)&bIm[cbase];
            vr[0] = fr.x; vr[1] = fr.y; vr[2] = fr.z; vr[3] = fr.w;
            vi[0] = fi.x; vi[1] = fi.y; vi[2] = fi.z; vi[3] = fi.w;
        }
        // canonical local: q=8 (reg bit1), q=9 (reg bit0)
        {
            float c, s;
            __sincosf(ry[8] * 0.5f, &s, &c);
            RY_PAIR(0, 2, c, s) RY_PAIR(1, 3, c, s)
            __sincosf(ry[9] * 0.5f, &s, &c);
            RY_PAIR(0, 1, c, s) RY_PAIR(2, 3, c, s)
        }

        // ================= CRZ ring diagonal (canonical) =================
        {
            const int hb = (w << 6) | lane;      // d-bits [9:2]
            float common = 0.f;
            #pragma unroll
            for (int q = 0; q <= 6; ++q) {       // control pos 9-q, target pos 8-q (both >=2)
                const float bq  = (float)((hb >> (7 - q)) & 1);
                const float bq1 = (float)((hb >> (6 - q)) & 1);
                common += crz[q] * bq * (bq1 - 0.5f);
            }
            const float b2 = (float)(hb & 1);          // d-bit2
            const float b9 = (float)((hb >> 7) & 1);   // d-bit9
            const float t7 = crz[7], t8 = crz[8], t9 = crz[9];
            #pragma unroll
            for (int r = 0; r < 4; ++r) {
                const float r1 = (float)((r >> 1) & 1);  // d-bit1
                const float r0 = (float)(r & 1);         // d-bit0
                const float ph = common
                               + t7 * b2 * (r1 - 0.5f)
                               + t8 * r1 * (r0 - 0.5f)
                               + t9 * r0 * (b9 - 0.5f);
                cmul_ph(vr[r], vi[r], ph);
            }
        }
        // NOTE: next block's transpose reuses buffer A; the barrier inside
        // buffer-B's transpose above already ordered all buffer-A reads.
    }

    // write out (canonical): 4 consecutive float2 per thread
    float2* out = psi + pt * DIM + cbase;
    *(float4*)&out[0] = make_float4(vr[0], vi[0], vr[1], vi[1]);
    *(float4*)&out[2] = make_float4(vr[2], vi[2], vr[3], vi[3]);
}

// ---------------------------------------------------------------------------
// Kernel B: fused Gram row + reduction + finalize.
// Block i: stage psi_i in LDS; thread pair (2j, 2j+1) computes halves of
// <psi_i|psi_j>; block-reduce polarity & sum(K^2); one atomicAdd pair per
// block; the last block to finish computes the output scalar.
// ---------------------------------------------------------------------------
__global__ __launch_bounds__(256)
void gramrow_kernel(const float2* __restrict__ psi,
                    const float* __restrict__ labels,
                    double* __restrict__ acc,
                    int* __restrict__ cnt,
                    float* __restrict__ out)
{
    __shared__ float4 sA[DIM / 2];     // row i: (re0,im0,re1,im1) x 512
    __shared__ double sp[4], sk[4];

    const int i   = blockIdx.x;
    const int tid = threadIdx.x;

    const float4* rowi = (const float4*)(psi + (size_t)i * DIM);
    #pragma unroll
    for (int t = tid; t < DIM / 2; t += 256) sA[t] = rowi[t];
    __syncthreads();

    const int j   = tid >> 1;          // 0..127
    const int sub = tid & 1;           // which half of d-range
    const float4* rowj = (const float4*)(psi + (size_t)j * DIM) + sub * (DIM / 4);
    const float4* ai   = sA + sub * (DIM / 4);

    float gr = 0.f, gi = 0.f;
    #pragma unroll 8
    for (int t = 0; t < DIM / 4; ++t) {
        const float4 a = ai[t];        // LDS: broadcast within wave
        const float4 b = rowj[t];
        gr += a.x * b.x + a.y * b.y;
        gi += a.x * b.y - a.y * b.x;
        gr += a.z * b.z + a.w * b.w;
        gi += a.z * b.w - a.w * b.z;
    }
    gr += __shfl_xor(gr, 1, 64);
    gi += __shfl_xor(gi, 1, 64);

    double pol = 0.0, k2 = 0.0;
    if (sub == 0) {
        const float K  = gr * gr + gi * gi;
        const float ll = labels[i] * labels[j];
        pol = (double)(ll * K);
        k2  = (double)K * (double)K;
    }
    #pragma unroll
    for (int off = 1; off < 64; off <<= 1) {
        pol += __shfl_xor(pol, off, 64);
        k2  += __shfl_xor(k2,  off, 64);
    }
    const int wv = tid >> 6;
    if ((tid & 63) == 0) { sp[wv] = pol; sk[wv] = k2; }
    __syncthreads();
    if (tid == 0) {
        atomicAdd(&acc[0], sp[0] + sp[1] + sp[2] + sp[3]);
        atomicAdd(&acc[1], sk[0] + sk[1] + sk[2] + sk[3]);
        __threadfence();
        const int done = atomicAdd(cnt, 1);
        if (done == NPTS - 1) {
            const double p  = atomicAdd(&acc[0], 0.0);   // atomic read
            const double s2 = atomicAdd(&acc[1], 0.0);
            double sumL2 = 0.0;
            for (int t = 0; t < NPTS; ++t) {
                const double l = (double)labels[t];
                sumL2 += l * l;
            }
            out[0] = (float)(p / (sumL2 * sqrt(s2)));
        }
    }
}

// ---------------------------------------------------------------------------
extern "C" void kernel_launch(void* const* d_in, const int* in_sizes, int n_in,
                              void* d_out, int out_size, void* d_ws, size_t ws_size,
                              hipStream_t stream)
{
    const float* data   = (const float*)d_in[0];   // [128,100]
    const float* labels = (const float*)d_in[1];   // [128]
    const float* params = (const float*)d_in[2];   // [10,2,10]
    float* out = (float*)d_out;

    float2* psi = (float2*)d_ws;                                   // 1 MiB
    double* acc = (double*)((char*)d_ws + (size_t)(1u << 20));     // 16 B
    int*    cnt = (int*)   ((char*)d_ws + (size_t)(1u << 20) + 16);

    states_kernel<<<NPTS, 256, 0, stream>>>(data, params, psi, acc, cnt);
    gramrow_kernel<<<NPTS, 256, 0, stream>>>(psi, labels, acc, cnt, out);
}

// Round 5
// 96.324 us; speedup vs baseline: 1.3230x; 1.3230x over previous
//
#include <hip/hip_runtime.h>
#include <math.h>

#define NQ   10
#define DIM  1024
#define NB   10
#define NPTS 128
#define S2   0.70710678118654752440f

#define TS 32
#define KC 64
#define KSPLIT (DIM / KC)       // 16
#define NBLK_RED 64             // reduce_final grid

// ---------------------------------------------------------------------------
// helpers
// ---------------------------------------------------------------------------
__device__ __forceinline__ void cmul_ph(float& vr, float& vi, float ph) {
    float s, c;
    __sincosf(ph, &s, &c);
    const float ar = vr, ai = vi;
    vr = ar * c - ai * s;
    vi = ar * s + ai * c;
}

#define H_PAIR(i0, i1) {                                   \
    const float ar = vr[i0], ai = vi[i0];                  \
    const float br = vr[i1], bi = vi[i1];                  \
    vr[i0] = (ar + br) * S2;  vi[i0] = (ai + bi) * S2;     \
    vr[i1] = (ar - br) * S2;  vi[i1] = (ai - bi) * S2; }

#define RY_PAIR(i0, i1, c, s) {                            \
    const float ar = vr[i0], ai = vi[i0];                  \
    const float br = vr[i1], bi = vi[i1];                  \
    vr[i0] = c * ar - s * br;  vi[i0] = c * ai - s * bi;   \
    vr[i1] = s * ar + c * br;  vi[i1] = s * ai + c * bi; }

// ---------------------------------------------------------------------------
// Kernel A: simulate psi(x) = F(x, params)|0>. One block (256 thr) per point.
// State fully in registers: 4 amps/thread. (proven absmax 0.0, rounds 2-3)
//   canonical layout : d = w*256 + lane*4 + r   (reg bits = d-bits [1:0])
//   transposed layout: d = k*256 + lane*4 + w   (reg bits = d-bits [9:8])
// Qubit q acts on d-bit p = 9-q. Double-buffered transpose LDS: 2 barriers
// per circuit block.
// ---------------------------------------------------------------------------
__global__ __launch_bounds__(256)
void states_kernel(const float* __restrict__ data,
                   const float* __restrict__ params,
                   float2* __restrict__ psi,
                   double* __restrict__ acc,
                   int* __restrict__ cnt)
{
    __shared__ float aRe[DIM];
    __shared__ float aIm[DIM];
    __shared__ float bRe[DIM];
    __shared__ float bIm[DIM];

    const int tid  = threadIdx.x;
    const int w    = tid >> 6;
    const int lane = tid & 63;
    const int pt   = blockIdx.x;

    const int cbase = w * 256 + lane * 4;  // canonical amps: cbase + r
    const int tb    = lane * 4 + w;        // transposed amps: k*256 + tb

    if (pt == 0 && tid == 0) { acc[0] = 0.0; acc[1] = 0.0; cnt[0] = 0; }

    float vr[4], vi[4];
    vr[0] = vr[1] = vr[2] = vr[3] = 0.f;
    vi[0] = vi[1] = vi[2] = vi[3] = 0.f;
    if (tid == 0) vr[0] = 1.f;

    const float* x = data + pt * (NB * NQ);

    for (int j = 0; j < NB; ++j) {
        const float* ry  = params + j * 2 * NQ;  // RY angles
        const float* crz = ry + NQ;              // CRZ angles
        const float* xb  = x + j * NQ;           // RZ angles (data)

        // ================= H layer =================
        H_PAIR(0, 2) H_PAIR(1, 3)
        H_PAIR(0, 1) H_PAIR(2, 3)
        #pragma unroll
        for (int l = 0; l < 6; ++l) {
            const float sg = ((lane >> l) & 1) ? -1.f : 1.f;
            #pragma unroll
            for (int r = 0; r < 4; ++r) {
                const float ur = __shfl_xor(vr[r], 1 << l, 64);
                const float ui = __shfl_xor(vi[r], 1 << l, 64);
                vr[r] = (ur + sg * vr[r]) * S2;
                vi[r] = (ui + sg * vi[r]) * S2;
            }
        }
        // transpose canonical -> transposed (buffer A)
        *(float4*)&aRe[cbase] = make_float4(vr[0], vr[1], vr[2], vr[3]);
        *(float4*)&aIm[cbase] = make_float4(vi[0], vi[1], vi[2], vi[3]);
        __syncthreads();
        #pragma unroll
        for (int k = 0; k < 4; ++k) { vr[k] = aRe[k * 256 + tb]; vi[k] = aIm[k * 256 + tb]; }
        H_PAIR(0, 2) H_PAIR(1, 3)
        H_PAIR(0, 1) H_PAIR(2, 3)

        // ================= RZ diagonal (transposed) =================
        {
            const float x0 = xb[0], x1 = xb[1];
            float base_ph = -0.5f * (x0 + x1);
            #pragma unroll
            for (int q = 2; q < NQ; ++q)
                base_ph += (((tb >> (9 - q)) & 1) - 0.5f) * xb[q];
            cmul_ph(vr[0], vi[0], base_ph);
            cmul_ph(vr[1], vi[1], base_ph + x1);
            cmul_ph(vr[2], vi[2], base_ph + x0);
            cmul_ph(vr[3], vi[3], base_ph + x0 + x1);
        }

        // ================= RY layer =================
        {
            float c, s;
            __sincosf(ry[0] * 0.5f, &s, &c);
            RY_PAIR(0, 2, c, s) RY_PAIR(1, 3, c, s)
            __sincosf(ry[1] * 0.5f, &s, &c);
            RY_PAIR(0, 1, c, s) RY_PAIR(2, 3, c, s)
        }
        #pragma unroll
        for (int l = 0; l < 6; ++l) {
            float c, s;
            __sincosf(ry[7 - l] * 0.5f, &s, &c);
            const float ss = ((lane >> l) & 1) ? s : -s;
            #pragma unroll
            for (int r = 0; r < 4; ++r) {
                const float ur = __shfl_xor(vr[r], 1 << l, 64);
                const float ui = __shfl_xor(vi[r], 1 << l, 64);
                vr[r] = c * vr[r] + ss * ur;
                vi[r] = c * vi[r] + ss * ui;
            }
        }
        // transpose back transposed -> canonical (buffer B)
        #pragma unroll
        for (int k = 0; k < 4; ++k) { bRe[k * 256 + tb] = vr[k]; bIm[k * 256 + tb] = vi[k]; }
        __syncthreads();
        {
            const float4 fr = *(const float4*)&bRe[cbase];
            const float4 fi = *(const float4*)&bIm[cbase];
            vr[0] = fr.x; vr[1] = fr.y; vr[2] = fr.z; vr[3] = fr.w;
            vi[0] = fi.x; vi[1] = fi.y; vi[2] = fi.z; vi[3] = fi.w;
        }
        {
            float c, s;
            __sincosf(ry[8] * 0.5f, &s, &c);
            RY_PAIR(0, 2, c, s) RY_PAIR(1, 3, c, s)
            __sincosf(ry[9] * 0.5f, &s, &c);
            RY_PAIR(0, 1, c, s) RY_PAIR(2, 3, c, s)
        }

        // ================= CRZ ring diagonal (canonical) =================
        {
            const int hb = (w << 6) | lane;      // d-bits [9:2]
            float common = 0.f;
            #pragma unroll
            for (int q = 0; q <= 6; ++q) {
                const float bq  = (float)((hb >> (7 - q)) & 1);
                const float bq1 = (float)((hb >> (6 - q)) & 1);
                common += crz[q] * bq * (bq1 - 0.5f);
            }
            const float b2 = (float)(hb & 1);          // d-bit2
            const float b9 = (float)((hb >> 7) & 1);   // d-bit9
            const float t7 = crz[7], t8 = crz[8], t9 = crz[9];
            #pragma unroll
            for (int r = 0; r < 4; ++r) {
                const float r1 = (float)((r >> 1) & 1);
                const float r0 = (float)(r & 1);
                const float ph = common
                               + t7 * b2 * (r1 - 0.5f)
                               + t8 * r1 * (r0 - 0.5f)
                               + t9 * r0 * (b9 - 0.5f);
                cmul_ph(vr[r], vi[r], ph);
            }
        }
    }

    float2* out = psi + pt * DIM + cbase;
    *(float4*)&out[0] = make_float4(vr[0], vi[0], vr[1], vi[1]);
    *(float4*)&out[2] = make_float4(vr[2], vi[2], vr[3], vi[3]);
}

// ---------------------------------------------------------------------------
// Kernel B: tiled complex Gram (proven round 2). 32x32 tile x 16 K-chunks =
// 256 blocks. Coalesced float4 staging; A broadcast / Bt <=2-way LDS reads;
// 2x2 register accumulator per thread.
// ---------------------------------------------------------------------------
__global__ __launch_bounds__(256)
void gram_kernel(const float2* __restrict__ psi, float2* __restrict__ Gpart)
{
    __shared__ float2 A [TS][KC + 2];   // pitch 66 float2
    __shared__ float2 Bt[KC][TS + 2];   // pitch 34 float2

    const int tid  = threadIdx.x;
    const int bx   = blockIdx.x;
    const int ks   = bx & 15;
    const int tile = bx >> 4;
    const int ti   = tile >> 2, tj = tile & 3;
    const int kbase = ks * KC;

    #pragma unroll
    for (int it = 0; it < 2; ++it) {
        const int slot = it * 256 + tid;
        const int row  = slot >> 4;          // 0..31
        const int kq   = (slot & 15) << 2;   // 0,4,...,60
        const float4* sa = (const float4*)(psi + (ti * TS + row) * DIM + kbase + kq);
        const float4 a01 = sa[0], a23 = sa[1];
        *(float4*)&A[row][kq]     = a01;
        *(float4*)&A[row][kq + 2] = a23;
        const float4* sb = (const float4*)(psi + (tj * TS + row) * DIM + kbase + kq);
        const float4 b01 = sb[0], b23 = sb[1];
        Bt[kq + 0][row] = make_float2(b01.x, b01.y);
        Bt[kq + 1][row] = make_float2(b01.z, b01.w);
        Bt[kq + 2][row] = make_float2(b23.x, b23.y);
        Bt[kq + 3][row] = make_float2(b23.z, b23.w);
    }
    __syncthreads();

    const int ty = tid >> 4, tx = tid & 15;
    float g00r = 0.f, g00i = 0.f, g01r = 0.f, g01i = 0.f;
    float g10r = 0.f, g10i = 0.f, g11r = 0.f, g11i = 0.f;

    #pragma unroll 4
    for (int k = 0; k < KC; k += 2) {
        const float4 a0 = *(const float4*)&A[2 * ty    ][k];
        const float4 a1 = *(const float4*)&A[2 * ty + 1][k];
        const float4 b0 = *(const float4*)&Bt[k    ][2 * tx];
        const float4 b1 = *(const float4*)&Bt[k + 1][2 * tx];
        g00r += a0.x * b0.x + a0.y * b0.y;  g00i += a0.x * b0.y - a0.y * b0.x;
        g01r += a0.x * b0.z + a0.y * b0.w;  g01i += a0.x * b0.w - a0.y * b0.z;
        g10r += a1.x * b0.x + a1.y * b0.y;  g10i += a1.x * b0.y - a1.y * b0.x;
        g11r += a1.x * b0.z + a1.y * b0.w;  g11i += a1.x * b0.w - a1.y * b0.z;
        g00r += a0.z * b1.x + a0.w * b1.y;  g00i += a0.z * b1.y - a0.w * b1.x;
        g01r += a0.z * b1.z + a0.w * b1.w;  g01i += a0.z * b1.w - a0.w * b1.z;
        g10r += a1.z * b1.x + a1.w * b1.y;  g10i += a1.z * b1.y - a1.w * b1.x;
        g11r += a1.z * b1.z + a1.w * b1.w;  g11i += a1.z * b1.w - a1.w * b1.z;
    }

    float2* gp = Gpart + ks * (NPTS * NPTS);
    const int gr0 = ti * TS + 2 * ty, gc0 = tj * TS + 2 * tx;
    gp[(gr0    ) * NPTS + gc0    ] = make_float2(g00r, g00i);
    gp[(gr0    ) * NPTS + gc0 + 1] = make_float2(g01r, g01i);
    gp[(gr0 + 1) * NPTS + gc0    ] = make_float2(g10r, g10i);
    gp[(gr0 + 1) * NPTS + gc0 + 1] = make_float2(g11r, g11i);
}

// ---------------------------------------------------------------------------
// Kernel C: sum K-partials (coalesced), K = |G|^2, reduce polarity & sum(K^2);
// last-finishing block (atomic counter, proven round 3) writes the scalar.
// ---------------------------------------------------------------------------
__global__ __launch_bounds__(256)
void reduce_final(const float2* __restrict__ Gpart,
                  const float* __restrict__ labels,
                  double* __restrict__ acc,
                  int* __restrict__ cnt,
                  float* __restrict__ out)
{
    const int idx = blockIdx.x * 256 + threadIdx.x;   // 0..16383
    float gr = 0.f, gi = 0.f;
    #pragma unroll
    for (int p = 0; p < KSPLIT; ++p) {
        const float2 g = Gpart[p * (NPTS * NPTS) + idx];
        gr += g.x; gi += g.y;
    }
    const int i  = idx >> 7;
    const int jj = idx & (NPTS - 1);
    const float K = gr * gr + gi * gi;
    double pol = (double)(labels[i] * labels[jj]) * (double)K;
    double k2  = (double)K * (double)K;
    #pragma unroll
    for (int off = 1; off < 64; off <<= 1) {
        pol += __shfl_xor(pol, off, 64);
        k2  += __shfl_xor(k2,  off, 64);
    }
    __shared__ double sp[4], sk[4];
    const int wv = threadIdx.x >> 6;
    if ((threadIdx.x & 63) == 0) { sp[wv] = pol; sk[wv] = k2; }
    __syncthreads();
    if (threadIdx.x == 0) {
        atomicAdd(&acc[0], sp[0] + sp[1] + sp[2] + sp[3]);
        atomicAdd(&acc[1], sk[0] + sk[1] + sk[2] + sk[3]);
        __threadfence();
        const int done = atomicAdd(cnt, 1);
        if (done == NBLK_RED - 1) {
            const double p  = atomicAdd(&acc[0], 0.0);   // atomic read
            const double s2 = atomicAdd(&acc[1], 0.0);
            double sumL2 = 0.0;
            for (int t = 0; t < NPTS; ++t) {
                const double l = (double)labels[t];
                sumL2 += l * l;
            }
            out[0] = (float)(p / (sumL2 * sqrt(s2)));
        }
    }
}

// ---------------------------------------------------------------------------
extern "C" void kernel_launch(void* const* d_in, const int* in_sizes, int n_in,
                              void* d_out, int out_size, void* d_ws, size_t ws_size,
                              hipStream_t stream)
{
    const float* data   = (const float*)d_in[0];   // [128,100]
    const float* labels = (const float*)d_in[1];   // [128]
    const float* params = (const float*)d_in[2];   // [10,2,10]
    float* out = (float*)d_out;

    float2* psi   = (float2*)d_ws;                                   // 1 MiB
    float2* Gpart = (float2*)((char*)d_ws + (size_t)(1u << 20));     // 2 MiB
    double* acc   = (double*)((char*)d_ws + (size_t)(3u << 20));     // 16 B
    int*    cnt   = (int*)   ((char*)d_ws + (size_t)(3u << 20) + 16);

    states_kernel<<<NPTS, 256, 0, stream>>>(data, params, psi, acc, cnt);
    gram_kernel<<<256, 256, 0, stream>>>(psi, Gpart);
    reduce_final<<<NBLK_RED, 256, 0, stream>>>(Gpart, labels, acc, cnt, out);
}

// Round 6
// 93.987 us; speedup vs baseline: 1.3559x; 1.0249x over previous
//
#include <hip/hip_runtime.h>
#include <math.h>

#define NQ   10
#define DIM  1024
#define NB   10
#define NPTS 128
#define S2   0.70710678118654752440f

#define TS 32
#define KC 64
#define KSPLIT (DIM / KC)       // 16
#define NBLK_RED 64             // reduce_final grid

// ---------------------------------------------------------------------------
// helpers
// ---------------------------------------------------------------------------
__device__ __forceinline__ void cmul_ph(float& vr, float& vi, float ph) {
    float s, c;
    __sincosf(ph, &s, &c);
    const float ar = vr, ai = vi;
    vr = ar * c - ai * s;
    vi = ar * s + ai * c;
}

__device__ __forceinline__ void cmul_cs(float& vr, float& vi, float c, float s) {
    const float ar = vr, ai = vi;
    vr = ar * c - ai * s;
    vi = ar * s + ai * c;
}

#define H_PAIR(i0, i1) {                                   \
    const float ar = vr[i0], ai = vi[i0];                  \
    const float br = vr[i1], bi = vi[i1];                  \
    vr[i0] = (ar + br) * S2;  vi[i0] = (ai + bi) * S2;     \
    vr[i1] = (ar - br) * S2;  vi[i1] = (ai - bi) * S2; }

#define RY_PAIR(i0, i1, c, s) {                            \
    const float ar = vr[i0], ai = vi[i0];                  \
    const float br = vr[i1], bi = vi[i1];                  \
    vr[i0] = c * ar - s * br;  vi[i0] = c * ai - s * bi;   \
    vr[i1] = s * ar + c * br;  vi[i1] = s * ai + c * bi; }

// ---------------------------------------------------------------------------
// Kernel A: simulate psi(x) = F(x, params)|0>. One block (256 thr) per point.
// State fully in registers: 4 amps/thread (proven absmax 0.0, rounds 2-5).
//   canonical layout : d = w*256 + lane*4 + r   (reg bits = d-bits [1:0])
//   transposed layout: d = k*256 + lane*4 + w   (reg bits = d-bits [9:8])
// Qubit q acts on d-bit p = 9-q.
// NEW: all angles + uniform sincos tables staged in LDS ONCE at entry, so the
// main loop has zero global loads and only data-dependent sincos (5/block).
// ---------------------------------------------------------------------------
__global__ __launch_bounds__(256)
void states_kernel(const float* __restrict__ data,
                   const float* __restrict__ params,
                   float2* __restrict__ psi,
                   double* __restrict__ acc,
                   int* __restrict__ cnt)
{
    __shared__ float aRe[DIM];
    __shared__ float aIm[DIM];
    __shared__ float bRe[DIM];
    __shared__ float bIm[DIM];
    __shared__ float sXb [NB * NQ];    // data angles for this point
    __shared__ float sRyC[NB * NQ];    // cos(ry/2)
    __shared__ float sRyS[NB * NQ];    // sin(ry/2)
    __shared__ float sCrz[NB * NQ];    // crz angles
    __shared__ float sCis[NB][6];      // per-block RZ rotors: cis(x0),cis(x1),cis(x0+x1)

    const int tid  = threadIdx.x;
    const int w    = tid >> 6;
    const int lane = tid & 63;
    const int pt   = blockIdx.x;

    const int cbase = w * 256 + lane * 4;  // canonical amps: cbase + r
    const int tb    = lane * 4 + w;        // transposed amps: k*256 + tb

    if (pt == 0 && tid == 0) { acc[0] = 0.0; acc[1] = 0.0; cnt[0] = 0; }

    // ---------------- one-time staging ----------------
    if (tid < NB * NQ) {
        sXb[tid] = data[pt * (NB * NQ) + tid];
    } else if (tid < 2 * NB * NQ) {
        const int t = tid - NB * NQ;       // 0..99
        const int j = t / NQ, q = t - j * NQ;
        const float ry = params[j * 2 * NQ + q];
        float s, c;
        __sincosf(0.5f * ry, &s, &c);
        sRyC[t] = c; sRyS[t] = s;
        sCrz[t] = params[j * 2 * NQ + NQ + q];
    }
    __syncthreads();
    if (tid < NB) {
        const float x0 = sXb[tid * NQ + 0], x1 = sXb[tid * NQ + 1];
        float s0, c0, s1, c1;
        __sincosf(x0, &s0, &c0);
        __sincosf(x1, &s1, &c1);
        sCis[tid][0] = c0; sCis[tid][1] = s0;
        sCis[tid][2] = c1; sCis[tid][3] = s1;
        sCis[tid][4] = c0 * c1 - s0 * s1;
        sCis[tid][5] = c0 * s1 + s0 * c1;
    }
    __syncthreads();

    float vr[4], vi[4];
    vr[0] = vr[1] = vr[2] = vr[3] = 0.f;
    vi[0] = vi[1] = vi[2] = vi[3] = 0.f;
    if (tid == 0) vr[0] = 1.f;

    for (int j = 0; j < NB; ++j) {
        const int j10 = j * NQ;

        // ================= H layer =================
        H_PAIR(0, 2) H_PAIR(1, 3)
        H_PAIR(0, 1) H_PAIR(2, 3)
        #pragma unroll
        for (int l = 0; l < 6; ++l) {
            const float sg = ((lane >> l) & 1) ? -1.f : 1.f;
            #pragma unroll
            for (int r = 0; r < 4; ++r) {
                const float ur = __shfl_xor(vr[r], 1 << l, 64);
                const float ui = __shfl_xor(vi[r], 1 << l, 64);
                vr[r] = (ur + sg * vr[r]) * S2;
                vi[r] = (ui + sg * vi[r]) * S2;
            }
        }
        // transpose canonical -> transposed (buffer A)
        *(float4*)&aRe[cbase] = make_float4(vr[0], vr[1], vr[2], vr[3]);
        *(float4*)&aIm[cbase] = make_float4(vi[0], vi[1], vi[2], vi[3]);
        __syncthreads();
        #pragma unroll
        for (int k = 0; k < 4; ++k) { vr[k] = aRe[k * 256 + tb]; vi[k] = aIm[k * 256 + tb]; }
        H_PAIR(0, 2) H_PAIR(1, 3)
        H_PAIR(0, 1) H_PAIR(2, 3)

        // ================= RZ diagonal (transposed) =================
        // phases: base + {0, x1, x0, x0+x1}; 1 sincos + 3 rotor products
        {
            float bp = -0.5f * (sXb[j10 + 0] + sXb[j10 + 1]);
            #pragma unroll
            for (int q = 2; q < NQ; ++q)
                bp += (((tb >> (9 - q)) & 1) - 0.5f) * sXb[j10 + q];
            float sb, cb;
            __sincosf(bp, &sb, &cb);
            const float c0 = sCis[j][0], s0 = sCis[j][1];
            const float c1 = sCis[j][2], s1 = sCis[j][3];
            const float c01 = sCis[j][4], s01 = sCis[j][5];
            cmul_cs(vr[0], vi[0], cb, sb);
            cmul_cs(vr[1], vi[1], cb * c1 - sb * s1, sb * c1 + cb * s1);
            cmul_cs(vr[2], vi[2], cb * c0 - sb * s0, sb * c0 + cb * s0);
            cmul_cs(vr[3], vi[3], cb * c01 - sb * s01, sb * c01 + cb * s01);
        }

        // ================= RY layer (all angles from LDS tables) =========
        {
            const float c0 = sRyC[j10 + 0], s0 = sRyS[j10 + 0];
            RY_PAIR(0, 2, c0, s0) RY_PAIR(1, 3, c0, s0)
            const float c1 = sRyC[j10 + 1], s1 = sRyS[j10 + 1];
            RY_PAIR(0, 1, c1, s1) RY_PAIR(2, 3, c1, s1)
        }
        #pragma unroll
        for (int l = 0; l < 6; ++l) {
            const float c = sRyC[j10 + 7 - l];
            const float s = sRyS[j10 + 7 - l];
            const float ss = ((lane >> l) & 1) ? s : -s;
            #pragma unroll
            for (int r = 0; r < 4; ++r) {
                const float ur = __shfl_xor(vr[r], 1 << l, 64);
                const float ui = __shfl_xor(vi[r], 1 << l, 64);
                vr[r] = c * vr[r] + ss * ur;
                vi[r] = c * vi[r] + ss * ui;
            }
        }
        // transpose back transposed -> canonical (buffer B)
        #pragma unroll
        for (int k = 0; k < 4; ++k) { bRe[k * 256 + tb] = vr[k]; bIm[k * 256 + tb] = vi[k]; }
        __syncthreads();
        {
            const float4 fr = *(const float4*)&bRe[cbase];
            const float4 fi = *(const float4*)&bIm[cbase];
            vr[0] = fr.x; vr[1] = fr.y; vr[2] = fr.z; vr[3] = fr.w;
            vi[0] = fi.x; vi[1] = fi.y; vi[2] = fi.z; vi[3] = fi.w;
        }
        {
            const float c8 = sRyC[j10 + 8], s8 = sRyS[j10 + 8];
            RY_PAIR(0, 2, c8, s8) RY_PAIR(1, 3, c8, s8)
            const float c9 = sRyC[j10 + 9], s9 = sRyS[j10 + 9];
            RY_PAIR(0, 1, c9, s9) RY_PAIR(2, 3, c9, s9)
        }

        // ================= CRZ ring diagonal (canonical) =================
        {
            const int hb = (w << 6) | lane;      // d-bits [9:2]
            float common = 0.f;
            #pragma unroll
            for (int q = 0; q <= 6; ++q) {
                const float bq  = (float)((hb >> (7 - q)) & 1);
                const float bq1 = (float)((hb >> (6 - q)) & 1);
                common += sCrz[j10 + q] * bq * (bq1 - 0.5f);
            }
            const float b2 = (float)(hb & 1);          // d-bit2
            const float b9 = (float)((hb >> 7) & 1);   // d-bit9
            const float t7 = sCrz[j10 + 7], t8 = sCrz[j10 + 8], t9 = sCrz[j10 + 9];
            #pragma unroll
            for (int r = 0; r < 4; ++r) {
                const float r1 = (float)((r >> 1) & 1);
                const float r0 = (float)(r & 1);
                const float ph = common
                               + t7 * b2 * (r1 - 0.5f)
                               + t8 * r1 * (r0 - 0.5f)
                               + t9 * r0 * (b9 - 0.5f);
                cmul_ph(vr[r], vi[r], ph);
            }
        }
    }

    float2* out = psi + pt * DIM + cbase;
    *(float4*)&out[0] = make_float4(vr[0], vi[0], vr[1], vi[1]);
    *(float4*)&out[2] = make_float4(vr[2], vi[2], vr[3], vi[3]);
}

// ---------------------------------------------------------------------------
// Kernel B: tiled complex Gram (proven round 2/5). 32x32 tile x 16 K-chunks =
// 256 blocks. Coalesced float4 staging; A broadcast / Bt <=2-way LDS reads;
// 2x2 register accumulator per thread.
// ---------------------------------------------------------------------------
__global__ __launch_bounds__(256)
void gram_kernel(const float2* __restrict__ psi, float2* __restrict__ Gpart)
{
    __shared__ float2 A [TS][KC + 2];   // pitch 66 float2
    __shared__ float2 Bt[KC][TS + 2];   // pitch 34 float2

    const int tid  = threadIdx.x;
    const int bx   = blockIdx.x;
    const int ks   = bx & 15;
    const int tile = bx >> 4;
    const int ti   = tile >> 2, tj = tile & 3;
    const int kbase = ks * KC;

    #pragma unroll
    for (int it = 0; it < 2; ++it) {
        const int slot = it * 256 + tid;
        const int row  = slot >> 4;          // 0..31
        const int kq   = (slot & 15) << 2;   // 0,4,...,60
        const float4* sa = (const float4*)(psi + (ti * TS + row) * DIM + kbase + kq);
        const float4 a01 = sa[0], a23 = sa[1];
        *(float4*)&A[row][kq]     = a01;
        *(float4*)&A[row][kq + 2] = a23;
        const float4* sb = (const float4*)(psi + (tj * TS + row) * DIM + kbase + kq);
        const float4 b01 = sb[0], b23 = sb[1];
        Bt[kq + 0][row] = make_float2(b01.x, b01.y);
        Bt[kq + 1][row] = make_float2(b01.z, b01.w);
        Bt[kq + 2][row] = make_float2(b23.x, b23.y);
        Bt[kq + 3][row] = make_float2(b23.z, b23.w);
    }
    __syncthreads();

    const int ty = tid >> 4, tx = tid & 15;
    float g00r = 0.f, g00i = 0.f, g01r = 0.f, g01i = 0.f;
    float g10r = 0.f, g10i = 0.f, g11r = 0.f, g11i = 0.f;

    #pragma unroll 4
    for (int k = 0; k < KC; k += 2) {
        const float4 a0 = *(const float4*)&A[2 * ty    ][k];
        const float4 a1 = *(const float4*)&A[2 * ty + 1][k];
        const float4 b0 = *(const float4*)&Bt[k    ][2 * tx];
        const float4 b1 = *(const float4*)&Bt[k + 1][2 * tx];
        g00r += a0.x * b0.x + a0.y * b0.y;  g00i += a0.x * b0.y - a0.y * b0.x;
        g01r += a0.x * b0.z + a0.y * b0.w;  g01i += a0.x * b0.w - a0.y * b0.z;
        g10r += a1.x * b0.x + a1.y * b0.y;  g10i += a1.x * b0.y - a1.y * b0.x;
        g11r += a1.x * b0.z + a1.y * b0.w;  g11i += a1.x * b0.w - a1.y * b0.z;
        g00r += a0.z * b1.x + a0.w * b1.y;  g00i += a0.z * b1.y - a0.w * b1.x;
        g01r += a0.z * b1.z + a0.w * b1.w;  g01i += a0.z * b1.w - a0.w * b1.z;
        g10r += a1.z * b1.x + a1.w * b1.y;  g10i += a1.z * b1.y - a1.w * b1.x;
        g11r += a1.z * b1.z + a1.w * b1.w;  g11i += a1.z * b1.w - a1.w * b1.z;
    }

    float2* gp = Gpart + ks * (NPTS * NPTS);
    const int gr0 = ti * TS + 2 * ty, gc0 = tj * TS + 2 * tx;
    gp[(gr0    ) * NPTS + gc0    ] = make_float2(g00r, g00i);
    gp[(gr0    ) * NPTS + gc0 + 1] = make_float2(g01r, g01i);
    gp[(gr0 + 1) * NPTS + gc0    ] = make_float2(g10r, g10i);
    gp[(gr0 + 1) * NPTS + gc0 + 1] = make_float2(g11r, g11i);
}

// ---------------------------------------------------------------------------
// Kernel C: sum K-partials (coalesced), K = |G|^2, reduce polarity & sum(K^2);
// last-finishing block (atomic counter, proven) writes the scalar.
// ---------------------------------------------------------------------------
__global__ __launch_bounds__(256)
void reduce_final(const float2* __restrict__ Gpart,
                  const float* __restrict__ labels,
                  double* __restrict__ acc,
                  int* __restrict__ cnt,
                  float* __restrict__ out)
{
    const int idx = blockIdx.x * 256 + threadIdx.x;   // 0..16383
    float gr = 0.f, gi = 0.f;
    #pragma unroll
    for (int p = 0; p < KSPLIT; ++p) {
        const float2 g = Gpart[p * (NPTS * NPTS) + idx];
        gr += g.x; gi += g.y;
    }
    const int i  = idx >> 7;
    const int jj = idx & (NPTS - 1);
    const float K = gr * gr + gi * gi;
    double pol = (double)(labels[i] * labels[jj]) * (double)K;
    double k2  = (double)K * (double)K;
    #pragma unroll
    for (int off = 1; off < 64; off <<= 1) {
        pol += __shfl_xor(pol, off, 64);
        k2  += __shfl_xor(k2,  off, 64);
    }
    __shared__ double sp[4], sk[4];
    const int wv = threadIdx.x >> 6;
    if ((threadIdx.x & 63) == 0) { sp[wv] = pol; sk[wv] = k2; }
    __syncthreads();
    if (threadIdx.x == 0) {
        atomicAdd(&acc[0], sp[0] + sp[1] + sp[2] + sp[3]);
        atomicAdd(&acc[1], sk[0] + sk[1] + sk[2] + sk[3]);
        __threadfence();
        const int done = atomicAdd(cnt, 1);
        if (done == NBLK_RED - 1) {
            const double p  = atomicAdd(&acc[0], 0.0);   // atomic read
            const double s2 = atomicAdd(&acc[1], 0.0);
            double sumL2 = 0.0;
            for (int t = 0; t < NPTS; ++t) {
                const double l = (double)labels[t];
                sumL2 += l * l;
            }
            out[0] = (float)(p / (sumL2 * sqrt(s2)));
        }
    }
}

// ---------------------------------------------------------------------------
extern "C" void kernel_launch(void* const* d_in, const int* in_sizes, int n_in,
                              void* d_out, int out_size, void* d_ws, size_t ws_size,
                              hipStream_t stream)
{
    const float* data   = (const float*)d_in[0];   // [128,100]
    const float* labels = (const float*)d_in[1];   // [128]
    const float* params = (const float*)d_in[2];   // [10,2,10]
    float* out = (float*)d_out;

    float2* psi   = (float2*)d_ws;                                   // 1 MiB
    float2* Gpart = (float2*)((char*)d_ws + (size_t)(1u << 20));     // 2 MiB
    double* acc   = (double*)((char*)d_ws + (size_t)(3u << 20));     // 16 B
    int*    cnt   = (int*)   ((char*)d_ws + (size_t)(3u << 20) + 16);

    states_kernel<<<NPTS, 256, 0, stream>>>(data, params, psi, acc, cnt);
    gram_kernel<<<256, 256, 0, stream>>>(psi, Gpart);
    reduce_final<<<NBLK_RED, 256, 0, stream>>>(Gpart, labels, acc, cnt, out);
}